// Round 1
// baseline (81.020 us; speedup 1.0000x reference)
//
#include <hip/hip_runtime.h>
#include <stdint.h>

#define OUT_F 8192
#define IN_F  8192
#define NGRP  1048576      // OUT*IN/GS
#define BATCH 64
#define QROWS 32           // GS/2 packed rows
#define BK    128
#define NIT   (IN_F / BK)  // 64

typedef short short8_t __attribute__((ext_vector_type(8)));
typedef float f32x4    __attribute__((ext_vector_type(4)));

static __device__ __forceinline__ float bf2f(uint32_t u) {
  return __uint_as_float(u << 16);
}
static __device__ __forceinline__ uint32_t f2bf(float f) {
  uint32_t u = __float_as_uint(f);
  return (u + 0x7fffu + ((u >> 16) & 1u)) >> 16;  // RNE
}

// ---- pre-pass 1: x fp32 -> bf16 (stored as ushort) ----
__global__ void cvt_x_kernel(const float* __restrict__ x, ushort* __restrict__ xb, int n4) {
  int i = blockIdx.x * blockDim.x + threadIdx.x;
  if (i < n4) {
    float4 v = ((const float4*)x)[i];
    ushort4 o;
    o.x = (ushort)f2bf(v.x); o.y = (ushort)f2bf(v.y);
    o.z = (ushort)f2bf(v.z); o.w = (ushort)f2bf(v.w);
    ((ushort4*)xb)[i] = o;
  }
}

// ---- pre-pass 2: pack per-group (bf16(scale), bf16(scale*zero)) into one uint ----
__global__ void pack_sz_kernel(const float* __restrict__ scale, const float* __restrict__ zero,
                               uint32_t* __restrict__ sz, int n4) {
  int i = blockIdx.x * blockDim.x + threadIdx.x;
  if (i < n4) {
    float4 s = ((const float4*)scale)[i];
    float4 z = ((const float4*)zero)[i];
    uint4 o;
    o.x = f2bf(s.x) | (f2bf(s.x * z.x) << 16);
    o.y = f2bf(s.y) | (f2bf(s.y * z.y) << 16);
    o.z = f2bf(s.z) | (f2bf(s.z * z.z) << 16);
    o.w = f2bf(s.w) | (f2bf(s.w * z.w) << 16);
    ((uint4*)sz)[i] = o;
  }
}

// ---- main fused dequant + GEMM kernel ----
// grid = 512: blockIdx = c*4 + rq ; c in [0,128), rq in [0,4)
// block owns output rows o = g*128 + c for g in {rbase..rbase+7} (hi) and {+32} (lo),
// rbase = rq*8. Each W_q element is read exactly once (both nibbles used here).
__global__ __launch_bounds__(256) void hqq_gemm_kernel(
    const int* __restrict__ Wq, const uint32_t* __restrict__ sz,
    const ushort* __restrict__ xb, const float* __restrict__ bias,
    float* __restrict__ out)
{
  const int t    = threadIdx.x;
  const int bid  = blockIdx.x;
  const int c    = bid >> 2;
  const int rq   = bid & 3;
  const int rbase = rq * 8;

  // swizzled bf16 W tile: 16 rows (8 hi + 8 lo) x BK cols, double buffered
  __shared__ ushort Wlds[2][16 * BK];

  const int lane = t & 63;
  const int wid  = t >> 6;     // 0..3 : M quarter (16 batch rows each)

  // staging assignment: thread -> (lr, i0)
  const int lr = t >> 5;            // 0..7  (W_q row within block)
  const int i0 = (t & 31) * 4;      // 0..124 (k within chunk, 4 int32 per thread)
  const int* __restrict__ wq_ptr = Wq + (size_t)(rbase + lr) * NGRP + (size_t)c * IN_F + i0;
  const uint32_t* __restrict__ sz_ptr = sz + (size_t)c * IN_F + i0;

  // MFMA A/B addressing
  const int tr    = lane & 15;          // B fragment: tile row (output row idx in tile)
  const int bcol0 = (lane >> 4) * 8;    // B fragment: k sub-offset
  const ushort* __restrict__ xrow = xb + (size_t)(wid * 16 + (lane & 15)) * IN_F + bcol0;

  f32x4 acc = {0.f, 0.f, 0.f, 0.f};

  auto stage = [&](int bsel, const int4& w, const uint4& szv) {
    ushort* dst = &Wlds[bsel][0];
    const int hidx = lr * BK + (i0 ^ ((lr & 7) << 3));   // XOR swizzle (8-elem groups)
    ushort4 hi4, lo4;
    {
      float s = bf2f(szv.x & 0xffffu), z = bf2f(szv.x >> 16);
      hi4.x = (ushort)f2bf((float)(w.x >> 4) * s - z);
      lo4.x = (ushort)f2bf((float)(w.x & 15) * s - z);
    }
    {
      float s = bf2f(szv.y & 0xffffu), z = bf2f(szv.y >> 16);
      hi4.y = (ushort)f2bf((float)(w.y >> 4) * s - z);
      lo4.y = (ushort)f2bf((float)(w.y & 15) * s - z);
    }
    {
      float s = bf2f(szv.z & 0xffffu), z = bf2f(szv.z >> 16);
      hi4.z = (ushort)f2bf((float)(w.z >> 4) * s - z);
      lo4.z = (ushort)f2bf((float)(w.z & 15) * s - z);
    }
    {
      float s = bf2f(szv.w & 0xffffu), z = bf2f(szv.w >> 16);
      hi4.w = (ushort)f2bf((float)(w.w >> 4) * s - z);
      lo4.w = (ushort)f2bf((float)(w.w & 15) * s - z);
    }
    *(ushort4*)&dst[hidx] = hi4;               // hi nibble rows 0..7
    *(ushort4*)&dst[hidx + 8 * BK] = lo4;      // lo nibble rows 8..15
  };

  // prologue: chunk 0 -> buf 0 ; issue chunk 1 loads
  int4  wq_n = *(const int4*)(wq_ptr);
  uint4 sz_n = *(const uint4*)(sz_ptr);
  stage(0, wq_n, sz_n);
  wq_n = *(const int4*)(wq_ptr + BK);
  sz_n = *(const uint4*)(sz_ptr + BK);
  __syncthreads();

  for (int it = 0; it < NIT; ++it) {
    const int curb = it & 1;
    const ushort* buf = &Wlds[curb][0];
    const int kg = it * BK;

    // MFMA phase on current buffer
    #pragma unroll
    for (int kk = 0; kk < BK / 32; ++kk) {
      short8_t a = *(const short8_t*)(xrow + kg + kk * 32);
      const int bidx = tr * BK + (((kk * 32) + bcol0) ^ ((tr & 7) << 3));
      short8_t b = *(const short8_t*)(buf + bidx);
      acc = __builtin_amdgcn_mfma_f32_16x16x32_bf16(a, b, acc, 0, 0, 0);
    }

    // dequant chunk it+1 into other buffer; prefetch chunk it+2
    if (it + 1 < NIT) {
      stage(curb ^ 1, wq_n, sz_n);
      if (it + 2 < NIT) {
        wq_n = *(const int4*)(wq_ptr + (size_t)(it + 2) * BK);
        sz_n = *(const uint4*)(sz_ptr + (size_t)(it + 2) * BK);
      }
    }
    __syncthreads();
  }

  // epilogue: lane l, reg j -> y[m, o]; C/D layout: col = lane&15, row = (lane>>4)*4 + j
  const int g = rbase + (tr & 7) + ((tr >> 3) << 5);  // tr<8: hi (g=rbase+tr), tr>=8: lo (+32)
  const int o = g * 128 + c;
  const float bo = bias[o];
  const int m0 = wid * 16 + (lane >> 4) * 4;
  #pragma unroll
  for (int j = 0; j < 4; ++j) {
    out[(size_t)(m0 + j) * OUT_F + o] = acc[j] + bo;
  }
}

// ---- correctness fallback if workspace is too small (slow, fp32) ----
__global__ void hqq_fallback_kernel(const float* __restrict__ x, const int* __restrict__ Wq,
                                    const float* __restrict__ scale, const float* __restrict__ zero,
                                    const float* __restrict__ bias, float* __restrict__ out)
{
  int idx = blockIdx.x * blockDim.x + threadIdx.x;  // [0, 64*8192)
  int b = idx >> 13;
  int o = idx & 8191;
  int g = o >> 7, cc = o & 127;
  int r = g & 31;
  bool hi = (g < 32);
  const int*   wrow = Wq    + (size_t)r  * NGRP + (size_t)cc * IN_F;
  const float* srow = scale + (size_t)cc * IN_F;
  const float* zrow = zero  + (size_t)cc * IN_F;
  const float* xrow = x     + (size_t)b  * IN_F;
  float acc = 0.f;
  for (int k = 0; k < IN_F; ++k) {
    int v = wrow[k];
    float nib = (float)(hi ? (v >> 4) : (v & 15));
    acc += xrow[k] * ((nib - zrow[k]) * srow[k]);
  }
  out[idx] = acc + bias[o];
}

extern "C" void kernel_launch(void* const* d_in, const int* in_sizes, int n_in,
                              void* d_out, int out_size, void* d_ws, size_t ws_size,
                              hipStream_t stream) {
  const float* x     = (const float*)d_in[0];
  const int*   Wq    = (const int*)d_in[1];
  const float* scale = (const float*)d_in[2];
  const float* zero  = (const float*)d_in[3];
  const float* bias  = (const float*)d_in[4];
  float* out = (float*)d_out;

  const size_t xb_bytes = (size_t)BATCH * IN_F * sizeof(ushort);   // 1 MB
  const size_t sz_bytes = (size_t)NGRP * sizeof(uint32_t);         // 4 MB

  if (ws_size < xb_bytes + sz_bytes) {
    hqq_fallback_kernel<<<(BATCH * OUT_F) / 256, 256, 0, stream>>>(x, Wq, scale, zero, bias, out);
    return;
  }

  ushort*   xb = (ushort*)d_ws;
  uint32_t* sz = (uint32_t*)((char*)d_ws + xb_bytes);

  cvt_x_kernel<<<(BATCH * IN_F / 4) / 256, 256, 0, stream>>>(x, xb, BATCH * IN_F / 4);
  pack_sz_kernel<<<(NGRP / 4) / 256, 256, 0, stream>>>(scale, zero, sz, NGRP / 4);
  hqq_gemm_kernel<<<512, 256, 0, stream>>>(Wq, sz, xb, bias, out);
}

// Round 2
// 62.971 us; speedup vs baseline: 1.2866x; 1.2866x over previous
//
#include <hip/hip_runtime.h>
#include <stdint.h>

#define OUT_F 8192
#define IN_F  8192
#define NGRP  1048576      // OUT*IN/GS
#define BATCH 64
#define BK    128
#define NIT   (IN_F / BK)  // 64

typedef short short8_t __attribute__((ext_vector_type(8)));
typedef float f32x4    __attribute__((ext_vector_type(4)));

static __device__ __forceinline__ float bf2f(uint32_t u) {
  return __uint_as_float(u << 16);
}
static __device__ __forceinline__ uint32_t f2bf(float f) {
  uint32_t u = __float_as_uint(f);
  return (u + 0x7fffu + ((u >> 16) & 1u)) >> 16;  // RNE
}
static __device__ __forceinline__ uint32_t cvt_pk_bf16(float a, float b) {
  uint32_t r;
  asm("v_cvt_pk_bf16_f32 %0, %1, %2" : "=v"(r) : "v"(a), "v"(b));
  return r;  // low16 = bf16(a), high16 = bf16(b)
}

// ---- pre-pass 1: x fp32 -> bf16 ----
__global__ void cvt_x_kernel(const float* __restrict__ x, ushort* __restrict__ xb, int n4) {
  int i = blockIdx.x * blockDim.x + threadIdx.x;
  if (i < n4) {
    float4 v = ((const float4*)x)[i];
    ushort4 o;
    o.x = (ushort)f2bf(v.x); o.y = (ushort)f2bf(v.y);
    o.z = (ushort)f2bf(v.z); o.w = (ushort)f2bf(v.w);
    ((ushort4*)xb)[i] = o;
  }
}

// ---- pre-pass 2: pack (bf16(scale), bf16(scale*zero)) per group ----
__global__ void pack_sz_kernel(const float* __restrict__ scale, const float* __restrict__ zero,
                               uint32_t* __restrict__ sz, int n4) {
  int i = blockIdx.x * blockDim.x + threadIdx.x;
  if (i < n4) {
    float4 s = ((const float4*)scale)[i];
    float4 z = ((const float4*)zero)[i];
    uint4 o;
    o.x = f2bf(s.x) | (f2bf(s.x * z.x) << 16);
    o.y = f2bf(s.y) | (f2bf(s.y * z.y) << 16);
    o.z = f2bf(s.z) | (f2bf(s.z * z.z) << 16);
    o.w = f2bf(s.w) | (f2bf(s.w * z.w) << 16);
    ((uint4*)sz)[i] = o;
  }
}

// ---- main fused dequant + GEMM ----
// KS = split-K factor. grid = 128c * 2rq * KS. Block owns 32 output rows:
// hi nibbles of Wq rows [rbase, rbase+16) (g = rbase+tr) and lo nibbles (g+32).
template<int KS>
__global__ __launch_bounds__(256) void hqq_gemm_kernel(
    const int* __restrict__ Wq, const uint32_t* __restrict__ sz,
    const ushort* __restrict__ xb, const float* __restrict__ bias,
    float* __restrict__ outp)
{
  constexpr int NITS = NIT / KS;
  const int t   = threadIdx.x;
  const int bid = blockIdx.x;
  const int ks  = bid % KS;
  const int rq  = (bid / KS) & 1;
  const int c   = bid / (2 * KS);
  const int rbase = rq * 16;

  __shared__ ushort Wlds[2][32 * BK];   // 16 KB, double buffered

  const int lane = t & 63;
  const int wid  = t >> 6;          // M quarter (16 batch rows)
  const int lr   = t >> 5;          // 0..7 : Wq row within half-block
  const int i0   = (t & 31) * 4;    // k offset within chunk (4 int32/thread)

  const size_t kbase = (size_t)ks * NITS * BK;
  const int* __restrict__ wqa = Wq + (size_t)(rbase + lr) * NGRP + (size_t)c * IN_F + kbase + i0;
  const int* __restrict__ wqb = wqa + (size_t)8 * NGRP;
  const uint32_t* __restrict__ szp = sz + (size_t)c * IN_F + kbase + i0;

  const int tr    = lane & 15;
  const int bcol0 = (lane >> 4) * 8;
  const ushort* __restrict__ xrow = xb + (size_t)(wid * 16 + tr) * IN_F + kbase + bcol0;

  f32x4 acc0 = {0.f, 0.f, 0.f, 0.f};
  f32x4 acc1 = {0.f, 0.f, 0.f, 0.f};

  const int sidx = lr * BK + (i0 ^ ((lr & 7) << 3));  // XOR-swizzled write index

  auto stage = [&](int bsel, const int4& wa, const int4& wb, const uint4& szv) {
    float s0 = bf2f(szv.x & 0xffffu), z0 = bf2f(szv.x >> 16);
    float s1 = bf2f(szv.y & 0xffffu), z1 = bf2f(szv.y >> 16);
    float s2 = bf2f(szv.z & 0xffffu), z2 = bf2f(szv.z >> 16);
    float s3 = bf2f(szv.w & 0xffffu), z3 = bf2f(szv.w >> 16);
    ushort* dst = &Wlds[bsel][0];
    uint2 h, l;
    // Wq row rbase+lr -> tile rows lr (hi) and lr+16 (lo)
    h.x = cvt_pk_bf16((float)(wa.x >> 4) * s0 - z0, (float)(wa.y >> 4) * s1 - z1);
    h.y = cvt_pk_bf16((float)(wa.z >> 4) * s2 - z2, (float)(wa.w >> 4) * s3 - z3);
    l.x = cvt_pk_bf16((float)(wa.x & 15) * s0 - z0, (float)(wa.y & 15) * s1 - z1);
    l.y = cvt_pk_bf16((float)(wa.z & 15) * s2 - z2, (float)(wa.w & 15) * s3 - z3);
    *(uint2*)&dst[sidx]           = h;
    *(uint2*)&dst[sidx + 16 * BK] = l;
    // Wq row rbase+lr+8 -> tile rows lr+8 (hi) and lr+24 (lo); (lr+8)&7 == lr&7
    h.x = cvt_pk_bf16((float)(wb.x >> 4) * s0 - z0, (float)(wb.y >> 4) * s1 - z1);
    h.y = cvt_pk_bf16((float)(wb.z >> 4) * s2 - z2, (float)(wb.w >> 4) * s3 - z3);
    l.x = cvt_pk_bf16((float)(wb.x & 15) * s0 - z0, (float)(wb.y & 15) * s1 - z1);
    l.y = cvt_pk_bf16((float)(wb.z & 15) * s2 - z2, (float)(wb.w & 15) * s3 - z3);
    *(uint2*)&dst[sidx + 8 * BK]  = h;
    *(uint2*)&dst[sidx + 24 * BK] = l;
  };

  // prologue: chunk 0 -> buf0; issue chunk-1 loads
  int4  wa_n = *(const int4*)wqa;
  int4  wb_n = *(const int4*)wqb;
  uint4 sz_n = *(const uint4*)szp;
  stage(0, wa_n, wb_n, sz_n);
  wa_n = *(const int4*)(wqa + BK);
  wb_n = *(const int4*)(wqb + BK);
  sz_n = *(const uint4*)(szp + BK);
  asm volatile("s_waitcnt lgkmcnt(0)" ::: "memory");
  __builtin_amdgcn_s_barrier();
  asm volatile("" ::: "memory");

  for (int it = 0; it < NITS; ++it) {
    const ushort* buf = &Wlds[it & 1][0];
    const int kg = it * BK;
    #pragma unroll
    for (int kk = 0; kk < 4; ++kk) {
      short8_t a = *(const short8_t*)(xrow + kg + kk * 32);
      const int col = (kk * 32 + bcol0) ^ ((tr & 7) << 3);
      short8_t b0 = *(const short8_t*)(buf + tr * BK + col);
      short8_t b1 = *(const short8_t*)(buf + (tr + 16) * BK + col);
      acc0 = __builtin_amdgcn_mfma_f32_16x16x32_bf16(a, b0, acc0, 0, 0, 0);
      acc1 = __builtin_amdgcn_mfma_f32_16x16x32_bf16(a, b1, acc1, 0, 0, 0);
    }
    if (it + 1 < NITS) {
      stage((it + 1) & 1, wa_n, wb_n, sz_n);
      if (it + 2 < NITS) {
        wa_n = *(const int4*)(wqa + (size_t)(it + 2) * BK);
        wb_n = *(const int4*)(wqb + (size_t)(it + 2) * BK);
        sz_n = *(const uint4*)(szp + (size_t)(it + 2) * BK);
      }
    }
    // raw barrier: order LDS, but do NOT drain vmcnt (keep prefetch in flight)
    asm volatile("s_waitcnt lgkmcnt(0)" ::: "memory");
    __builtin_amdgcn_s_barrier();
    asm volatile("" ::: "memory");
  }

  // epilogue. C/D: col = lane&15 (tile row -> o), row = (lane>>4)*4 + j (-> m)
  const int m0 = wid * 16 + (lane >> 4) * 4;
  const int o0 = (rbase + tr) * 128 + c;          // hi nibble rows
  const int o1 = (rbase + tr + 32) * 128 + c;     // lo nibble rows
  if constexpr (KS == 1) {
    const float b0v = bias[o0], b1v = bias[o1];
    #pragma unroll
    for (int j = 0; j < 4; ++j) {
      outp[(size_t)(m0 + j) * OUT_F + o0] = acc0[j] + b0v;
      outp[(size_t)(m0 + j) * OUT_F + o1] = acc1[j] + b1v;
    }
  } else {
    float* pp = outp + (size_t)ks * BATCH * OUT_F;
    #pragma unroll
    for (int j = 0; j < 4; ++j) {
      pp[(size_t)(m0 + j) * OUT_F + o0] = acc0[j];
      pp[(size_t)(m0 + j) * OUT_F + o1] = acc1[j];
    }
  }
}

// ---- split-K reduction (+bias), deterministic ----
__global__ __launch_bounds__(256) void reduce_kernel(const float* __restrict__ part,
                                                     const float* __restrict__ bias,
                                                     float* __restrict__ out)
{
  int i = blockIdx.x * blockDim.x + threadIdx.x;   // float4 index, 131072 total
  float4 a = ((const float4*)part)[i];
  float4 b = ((const float4*)(part + (size_t)1 * BATCH * OUT_F))[i];
  float4 c = ((const float4*)(part + (size_t)2 * BATCH * OUT_F))[i];
  float4 d = ((const float4*)(part + (size_t)3 * BATCH * OUT_F))[i];
  int o = (i * 4) & (OUT_F - 1);
  float4 bv = *(const float4*)(bias + o);
  float4 r;
  r.x = a.x + b.x + c.x + d.x + bv.x;
  r.y = a.y + b.y + c.y + d.y + bv.y;
  r.z = a.z + b.z + c.z + d.z + bv.z;
  r.w = a.w + b.w + c.w + d.w + bv.w;
  ((float4*)out)[i] = r;
}

// ---- correctness fallback (tiny ws), fp32 ----
__global__ void hqq_fallback_kernel(const float* __restrict__ x, const int* __restrict__ Wq,
                                    const float* __restrict__ scale, const float* __restrict__ zero,
                                    const float* __restrict__ bias, float* __restrict__ out)
{
  int idx = blockIdx.x * blockDim.x + threadIdx.x;
  int b = idx >> 13;
  int o = idx & 8191;
  int g = o >> 7, cc = o & 127;
  int r = g & 31;
  bool hi = (g < 32);
  const int*   wrow = Wq    + (size_t)r  * NGRP + (size_t)cc * IN_F;
  const float* srow = scale + (size_t)cc * IN_F;
  const float* zrow = zero  + (size_t)cc * IN_F;
  const float* xrow = x     + (size_t)b  * IN_F;
  float acc = 0.f;
  for (int k = 0; k < IN_F; ++k) {
    int v = wrow[k];
    float nib = (float)(hi ? (v >> 4) : (v & 15));
    acc += xrow[k] * ((nib - zrow[k]) * srow[k]);
  }
  out[idx] = acc + bias[o];
}

extern "C" void kernel_launch(void* const* d_in, const int* in_sizes, int n_in,
                              void* d_out, int out_size, void* d_ws, size_t ws_size,
                              hipStream_t stream) {
  const float* x     = (const float*)d_in[0];
  const int*   Wq    = (const int*)d_in[1];
  const float* scale = (const float*)d_in[2];
  const float* zero  = (const float*)d_in[3];
  const float* bias  = (const float*)d_in[4];
  float* out = (float*)d_out;

  const size_t xb_bytes   = (size_t)BATCH * IN_F * sizeof(ushort);       // 1 MB
  const size_t sz_bytes   = (size_t)NGRP * sizeof(uint32_t);             // 4 MB
  const size_t part_bytes = (size_t)4 * BATCH * OUT_F * sizeof(float);   // 8 MB

  if (ws_size >= xb_bytes + sz_bytes + part_bytes) {
    ushort*   xb   = (ushort*)d_ws;
    uint32_t* sz   = (uint32_t*)((char*)d_ws + xb_bytes);
    float*    part = (float*)((char*)d_ws + xb_bytes + sz_bytes);
    cvt_x_kernel<<<(BATCH * IN_F / 4) / 256, 256, 0, stream>>>(x, xb, BATCH * IN_F / 4);
    pack_sz_kernel<<<(NGRP / 4) / 256, 256, 0, stream>>>(scale, zero, sz, NGRP / 4);
    hqq_gemm_kernel<4><<<128 * 2 * 4, 256, 0, stream>>>(Wq, sz, xb, bias, part);
    reduce_kernel<<<(BATCH * OUT_F / 4) / 256, 256, 0, stream>>>(part, bias, out);
  } else if (ws_size >= xb_bytes + sz_bytes) {
    ushort*   xb = (ushort*)d_ws;
    uint32_t* sz = (uint32_t*)((char*)d_ws + xb_bytes);
    cvt_x_kernel<<<(BATCH * IN_F / 4) / 256, 256, 0, stream>>>(x, xb, BATCH * IN_F / 4);
    pack_sz_kernel<<<(NGRP / 4) / 256, 256, 0, stream>>>(scale, zero, sz, NGRP / 4);
    hqq_gemm_kernel<1><<<128 * 2, 256, 0, stream>>>(Wq, sz, xb, bias, out);
  } else {
    hqq_fallback_kernel<<<(BATCH * OUT_F) / 256, 256, 0, stream>>>(x, Wq, scale, zero, bias, out);
  }
}